// Round 1
// baseline (325.857 us; speedup 1.0000x reference)
//
#include <hip/hip_runtime.h>
#include <hip/hip_bf16.h>
#include <math.h>

#define L_LEN 110592   // 48*48*48
#define TILE 32
#define NT 3456        // tiles per batch
#define NCH 64         // scan chunks per batch
#define TPC 54         // tiles per chunk (NT/NCH)
#define STRX 72        // staged-x LDS row stride (bf16): 144B rows, 16B-aligned
#define STRC 136       // conv-out LDS row stride (bf16): 272B rows (2-way reads)
#define RESS 132       // resf row stride (f32): breaks 4-way write conflict

typedef float  floatx4 __attribute__((ext_vector_type(4)));
typedef short  short8  __attribute__((ext_vector_type(8)));
typedef short  short4v __attribute__((ext_vector_type(4)));

// fast silu: v * rcp(1+exp(-v))
__device__ __forceinline__ float fast_silu(float v) {
    return v * __builtin_amdgcn_rcpf(1.f + __expf(-v));
}
// fast softplus: max(d,0) + log(1+exp(-|d|))
__device__ __forceinline__ float fast_softplus(float d) {
    return fmaxf(d, 0.f) + __logf(1.f + __expf(-fabsf(d)));
}
__device__ __forceinline__ short f2bf(float f) {
    __hip_bfloat16 h = __float2bfloat16(f);
    return *reinterpret_cast<short*>(&h);
}
__device__ __forceinline__ float bf2f(short s) {
    __hip_bfloat16 h = *reinterpret_cast<__hip_bfloat16*>(&s);
    return __bfloat162float(h);
}
__device__ __forceinline__ short8 pack_bf8(float4 a, float4 b) {
    short8 r;
    r[0] = f2bf(a.x); r[1] = f2bf(a.y); r[2] = f2bf(a.z); r[3] = f2bf(a.w);
    r[4] = f2bf(b.x); r[5] = f2bf(b.y); r[6] = f2bf(b.z); r[7] = f2bf(b.w);
    return r;
}

// ---------------------------------------------------------------------------
// kW_w: transposed bf16 weight copies.
//   wti[n][k] = W_in[k][n] (ssm), wtr[n][k] = W_in[k][128+n] (res), k<64
//   wpt[n][k] = n<128 ? W_x[k][n] : W_dt[k][n-128], k<128
//   wot[n][k] = W_out[k][n], n<64, k<128
// ---------------------------------------------------------------------------
__global__ __launch_bounds__(256) void kW_w(
    const float* __restrict__ W_in, const float* __restrict__ W_x,
    const float* __restrict__ W_dt, const float* __restrict__ W_out,
    __hip_bfloat16* __restrict__ wti, __hip_bfloat16* __restrict__ wpt,
    __hip_bfloat16* __restrict__ wtr, __hip_bfloat16* __restrict__ wot)
{
    const int t = threadIdx.x;
    for (int idx = t; idx < 128 * 64; idx += 256) {
        int n = idx >> 6, k = idx & 63;
        wti[idx] = __float2bfloat16(W_in[k * 256 + n]);
        wtr[idx] = __float2bfloat16(W_in[k * 256 + 128 + n]);
    }
    for (int idx = t; idx < 256 * 128; idx += 256) {
        int n = idx >> 7, k = idx & 127;
        float v = (n < 128) ? W_x[k * 144 + n] : W_dt[k * 128 + (n - 128)];
        wpt[idx] = __float2bfloat16(v);
    }
    for (int idx = t; idx < 64 * 128; idx += 256) {
        int n = idx >> 7, k = idx & 127;
        wot[idx] = __float2bfloat16(W_out[k * 64 + n]);
    }
}

// ---------------------------------------------------------------------------
// kA (MFMA): cooperative bf16 x staging -> in-proj MFMA -> conv-in-registers
// (cross-lane shuffles) + silu -> projections -> s (bf16, [b][c][l]) + sums.
// LDS 15.6KB -> 8 blocks/CU target; conv reads full-f32 accumulators.
// ---------------------------------------------------------------------------
__global__ __launch_bounds__(256, 8) void kA(
    const float* __restrict__ x,
    const __hip_bfloat16* __restrict__ wti,
    const __hip_bfloat16* __restrict__ wpt,
    const float* __restrict__ conv_w, const float* __restrict__ conv_b,
    const float* __restrict__ b_dt,
    __hip_bfloat16* __restrict__ s, float* __restrict__ sums)
{
    __shared__ __align__(16) __hip_bfloat16 xbf[48 * STRX];  // 6912 B
    __shared__ __align__(16) __hip_bfloat16 xcb[32 * STRC];  // 8704 B

    const int t = threadIdx.x;
    const int lane = t & 63;
    const int w = t >> 6;
    const int quad = lane >> 4;
    const int lr = lane & 15;
    const int tile = blockIdx.x;
    const int b = blockIdx.y;
    const int l0 = tile * TILE;

    // ---- stage: x rows l0-1 .. l0+46 (48 rows x 64ch) -> bf16 LDS, once
    for (int idx = t; idx < 384; idx += 256) {
        const int row = idx >> 3, c8 = (idx & 7) << 3;
        const long gr = (long)l0 - 1 + row;
        float4 u0 = {0.f, 0.f, 0.f, 0.f}, u1 = {0.f, 0.f, 0.f, 0.f};
        if (gr >= 0 && gr < L_LEN) {
            const float* xp = x + (((long)b * L_LEN + gr) << 6) + c8;
            u0 = ((const float4*)xp)[0];
            u1 = ((const float4*)xp)[1];
        }
        *(short8*)&xbf[row * STRX + c8] = pack_bf8(u0, u1);
    }
    __syncthreads();

    // ---- phase 1: in-proj (M=48, N=128, K=64) + depthwise conv(4) + silu,
    //      conv done in accumulator registers via cross-lane shuffles.
    {
        floatx4 acc[3][2] = {};
        #pragma unroll
        for (int ks = 0; ks < 2; ++ks) {
            short8 bfr0 = *(const short8*)(wti + ((w * 32 + lr) << 6) + ks * 32 + quad * 8);
            short8 bfr1 = *(const short8*)(wti + ((w * 32 + 16 + lr) << 6) + ks * 32 + quad * 8);
            #pragma unroll
            for (int mt = 0; mt < 3; ++mt) {
                short8 afr = *(const short8*)&xbf[(mt * 16 + lr) * STRX + ks * 32 + quad * 8];
                acc[mt][0] = __builtin_amdgcn_mfma_f32_16x16x32_bf16(afr, bfr0, acc[mt][0], 0, 0, 0);
                acc[mt][1] = __builtin_amdgcn_mfma_f32_16x16x32_bf16(afr, bfr1, acc[mt][1], 0, 0, 0);
            }
        }
        // lane holds rows {mt*16 + quad*4 + r} for col w*32+jj*16+lr.
        // conv out[m] needs computed rows m..m+3; rows m+4..m+6 live in the
        // next quad (lane+16), wrapping into mt+1 when quad==3.
        const int srcLane = (((quad + 1) & 3) << 4) | lr;
        #pragma unroll
        for (int jj = 0; jj < 2; ++jj) {
            const int col = w * 32 + jj * 16 + lr;
            const float cw0 = conv_w[col],       cw1 = conv_w[128 + col];
            const float cw2 = conv_w[256 + col], cw3 = conv_w[384 + col];
            const float cb = conv_b[col];
            #pragma unroll
            for (int m = 0; m < 2; ++m) {
                float s0 = (quad == 0) ? acc[m + 1][jj][0] : acc[m][jj][0];
                float s1 = (quad == 0) ? acc[m + 1][jj][1] : acc[m][jj][1];
                float s2 = (quad == 0) ? acc[m + 1][jj][2] : acc[m][jj][2];
                const float e0 = __shfl(s0, srcLane);
                const float e1 = __shfl(s1, srcLane);
                const float e2 = __shfl(s2, srcLane);
                const float a0 = acc[m][jj][0], a1 = acc[m][jj][1];
                const float a2 = acc[m][jj][2], a3 = acc[m][jj][3];
                const int rb = m * 16 + quad * 4;
                xcb[(rb + 0) * STRC + col] =
                    __float2bfloat16(fast_silu(cb + cw0 * a0 + cw1 * a1 + cw2 * a2 + cw3 * a3));
                xcb[(rb + 1) * STRC + col] =
                    __float2bfloat16(fast_silu(cb + cw0 * a1 + cw1 * a2 + cw2 * a3 + cw3 * e0));
                xcb[(rb + 2) * STRC + col] =
                    __float2bfloat16(fast_silu(cb + cw0 * a2 + cw1 * a3 + cw2 * e0 + cw3 * e1));
                xcb[(rb + 3) * STRC + col] =
                    __float2bfloat16(fast_silu(cb + cw0 * a3 + cw1 * e0 + cw2 * e1 + cw3 * e2));
            }
        }
    }
    __syncthreads();

    // ---- phase 3: projections, s (channel-major, packed b64 stores) + sums
    {
        floatx4 accx[2][2] = {}, accd[2][2] = {};
        #pragma unroll
        for (int ks = 0; ks < 4; ++ks) {
            short8 afr[2];
            #pragma unroll
            for (int mt = 0; mt < 2; ++mt)
                afr[mt] = *(const short8*)&xcb[(mt * 16 + lr) * STRC + ks * 32 + quad * 8];
            #pragma unroll
            for (int j = 0; j < 2; ++j) {
                const int n = w * 32 + j * 16 + lr;
                short8 bx = *(const short8*)(wpt + (n << 7) + ks * 32 + quad * 8);
                short8 bd = *(const short8*)(wpt + ((n + 128) << 7) + ks * 32 + quad * 8);
                #pragma unroll
                for (int mt = 0; mt < 2; ++mt) {
                    accx[mt][j] = __builtin_amdgcn_mfma_f32_16x16x32_bf16(afr[mt], bx, accx[mt][j], 0, 0, 0);
                    accd[mt][j] = __builtin_amdgcn_mfma_f32_16x16x32_bf16(afr[mt], bd, accd[mt][j], 0, 0, 0);
                }
            }
        }
        float ps0 = 0.f, ps1 = 0.f;
        #pragma unroll
        for (int j = 0; j < 2; ++j) {
            const int col = w * 32 + j * 16 + lr;
            const float bdv = b_dt[col];
            __hip_bfloat16* sp = s + ((long)b * 128 + col) * L_LEN + l0 + quad * 4;
            float psl = 0.f;
            #pragma unroll
            for (int mt = 0; mt < 2; ++mt) {
                short4v pk;
                #pragma unroll
                for (int r = 0; r < 4; ++r) {
                    float dv = accd[mt][j][r] + bdv;
                    float sv = accx[mt][j][r] * fast_softplus(dv);
                    short h = f2bf(sv);
                    pk[r] = h;
                    psl += bf2f(h);
                }
                *(short4v*)(sp + mt * 16) = pk;
            }
            if (j == 0) ps0 = psl; else ps1 = psl;
        }
        ps0 += __shfl_xor(ps0, 16); ps0 += __shfl_xor(ps0, 32);
        ps1 += __shfl_xor(ps1, 16); ps1 += __shfl_xor(ps1, 32);
        const long sb = ((long)b * NT + tile) << 7;
        if (quad == 0)      sums[sb + w * 32 + lr] = ps0;
        else if (quad == 1) sums[sb + w * 32 + 16 + lr] = ps1;
    }
}

// ---------------------------------------------------------------------------
// kB1: per-chunk channel sums. grid(NCH, 2) x 256.
// ---------------------------------------------------------------------------
__global__ __launch_bounds__(256) void kB1(const float* __restrict__ sums,
                                           float* __restrict__ csum)
{
    __shared__ float ps[256];
    const int t = threadIdx.x;
    const int c = t & 127, h = t >> 7;
    const int ch = blockIdx.x, b = blockIdx.y;
    const long tb = ((long)b * NT + ch * TPC + h * 27) * 128 + c;
    float tot = 0.f;
    for (int j = 0; j < 27; j += 9) {
        float v[9];
        #pragma unroll
        for (int k = 0; k < 9; ++k) v[k] = sums[tb + (long)(j + k) * 128];
        #pragma unroll
        for (int k = 0; k < 9; ++k) tot += v[k];
    }
    ps[t] = tot;
    __syncthreads();
    if (t < 128) csum[((long)b * NCH + ch) * 128 + t] = ps[t] + ps[t + 128];
}

// ---------------------------------------------------------------------------
// kB2: exclusive scan over the 64 chunks, per (b, c). 1 block x 256.
// ---------------------------------------------------------------------------
__global__ __launch_bounds__(256) void kB2(float* __restrict__ csum)
{
    const int t = threadIdx.x;
    const int c = t & 127, b = t >> 7;
    const long base = (long)b * NCH * 128 + c;
    float run = 0.f;
    for (int ch = 0; ch < NCH; ch += 8) {
        float v[8];
        #pragma unroll
        for (int k = 0; k < 8; ++k) v[k] = csum[base + (long)(ch + k) * 128];
        #pragma unroll
        for (int k = 0; k < 8; ++k) {
            csum[base + (long)(ch + k) * 128] = run;
            run += v[k];
        }
    }
}

// ---------------------------------------------------------------------------
// kB3: rewrite sums -> exclusive tile prefix (chunk offset + in-chunk scan).
// grid(NCH, 2) x 128.
// ---------------------------------------------------------------------------
__global__ __launch_bounds__(128) void kB3(float* __restrict__ sums,
                                           const float* __restrict__ csum)
{
    const int c = threadIdx.x;
    const int ch = blockIdx.x, b = blockIdx.y;
    float run = csum[((long)b * NCH + ch) * 128 + c];
    const long tb = ((long)b * NT + ch * TPC) * 128 + c;
    for (int j = 0; j < TPC; j += 9) {
        float v[9];
        #pragma unroll
        for (int k = 0; k < 9; ++k) v[k] = sums[tb + (long)(j + k) * 128];
        #pragma unroll
        for (int k = 0; k < 9; ++k) {
            sums[tb + (long)(j + k) * 128] = run;
            run += v[k];
        }
    }
}

// ---------------------------------------------------------------------------
// kC (MFMA): staged bf16 x -> res-proj MFMA -> silu -> 2-way split scan
// (vector s loads, [b][c][l]) + gate -> out-proj MFMA -> residual + LN(64).
// ---------------------------------------------------------------------------
__global__ __launch_bounds__(256, 6) void kC(
    const float* __restrict__ x,
    const __hip_bfloat16* __restrict__ wtr,
    const __hip_bfloat16* __restrict__ wot,
    const float* __restrict__ gamma, const float* __restrict__ beta,
    const __hip_bfloat16* __restrict__ s, const float* __restrict__ offs,
    float* __restrict__ out)
{
    __shared__ float resf[32 * RESS];                   // 16.9 KB; reused as zbuf
    __shared__ __align__(16) char ubuf[32 * STRC * 2];  // 8704 B: xbf then ybf
    __shared__ float totbuf[256];                       // 1 KB

    __hip_bfloat16* const ybf = (__hip_bfloat16*)ubuf;
    __hip_bfloat16* const xbf = (__hip_bfloat16*)ubuf;  // phase-1 only

    const int t = threadIdx.x;
    const int lane = t & 63;
    const int w = t >> 6;
    const int quad = lane >> 4;
    const int lr = lane & 15;
    const int tile = blockIdx.x;
    const int b = blockIdx.y;
    const int l0 = tile * TILE;
    const long base = (long)b * L_LEN;

    // ---- stage: x rows l0..l0+31 -> bf16 LDS (1 unit per thread)
    {
        const int row = t >> 3, c8 = (t & 7) << 3;
        const float* xp = x + ((base + l0 + row) << 6) + c8;
        float4 u0 = ((const float4*)xp)[0], u1 = ((const float4*)xp)[1];
        *(short8*)&xbf[row * STRX + c8] = pack_bf8(u0, u1);
    }
    __syncthreads();

    // ---- phase 1: res-proj MFMA (M=32, N=128, K=64), silu -> resf[m][c]
    {
        floatx4 acc[2][2] = {};
        #pragma unroll
        for (int ks = 0; ks < 2; ++ks) {
            short8 bfr0 = *(const short8*)(wtr + ((w * 32 + lr) << 6) + ks * 32 + quad * 8);
            short8 bfr1 = *(const short8*)(wtr + ((w * 32 + 16 + lr) << 6) + ks * 32 + quad * 8);
            #pragma unroll
            for (int mt = 0; mt < 2; ++mt) {
                short8 afr = *(const short8*)&xbf[(mt * 16 + lr) * STRX + ks * 32 + quad * 8];
                acc[mt][0] = __builtin_amdgcn_mfma_f32_16x16x32_bf16(afr, bfr0, acc[mt][0], 0, 0, 0);
                acc[mt][1] = __builtin_amdgcn_mfma_f32_16x16x32_bf16(afr, bfr1, acc[mt][1], 0, 0, 0);
            }
        }
        #pragma unroll
        for (int mt = 0; mt < 2; ++mt)
            #pragma unroll
            for (int j = 0; j < 2; ++j) {
                const int col = w * 32 + j * 16 + lr;
                #pragma unroll
                for (int r = 0; r < 4; ++r)
                    resf[(mt * 16 + quad * 4 + r) * RESS + col] = fast_silu(acc[mt][j][r]);
            }
    }
    __syncthreads();   // also retires xbf before ybf overwrites ubuf

    // ---- phase 2: 2-way split scan + gate (all 256 threads), y -> ybf bf16
    {
        const int c = t & 127, h = t >> 7;
        const __hip_bfloat16* sp = s + ((long)b * 128 + c) * L_LEN + l0 + h * 16;
        short8 sv0 = *(const short8*)sp;
        short8 sv1 = *(const short8*)(sp + 8);
        float pfx[16];
        float run = 0.f;
        #pragma unroll
        for (int i = 0; i < 8; ++i) { run += bf2f(sv0[i]); pfx[i] = run; }
        #pragma unroll
        for (int i = 0; i < 8; ++i) { run += bf2f(sv1[i]); pfx[8 + i] = run; }
        totbuf[t] = run;
        __syncthreads();
        float off = offs[((long)b * NT + tile) * 128 + c];
        if (h) off += totbuf[c];
        #pragma unroll
        for (int q = 0; q < 16; ++q)
            ybf[(h * 16 + q) * STRC + c] =
                __float2bfloat16(resf[(h * 16 + q) * RESS + c] * (off + pfx[q]));
    }
    __syncthreads();

    // ---- phase 3: out-proj MFMA (M=32, N=64, K=128) -> zbuf (=resf) [m][68]
    {
        float* zbuf = resf;
        floatx4 acc[2] = {};
        const int n = w * 16 + lr;
        #pragma unroll
        for (int ks = 0; ks < 4; ++ks) {
            short8 bfr = *(const short8*)(wot + (n << 7) + ks * 32 + quad * 8);
            #pragma unroll
            for (int mt = 0; mt < 2; ++mt) {
                short8 afr = *(const short8*)&ybf[(mt * 16 + lr) * STRC + ks * 32 + quad * 8];
                acc[mt] = __builtin_amdgcn_mfma_f32_16x16x32_bf16(afr, bfr, acc[mt], 0, 0, 0);
            }
        }
        #pragma unroll
        for (int mt = 0; mt < 2; ++mt)
            #pragma unroll
            for (int r = 0; r < 4; ++r)
                zbuf[(mt * 16 + quad * 4 + r) * 68 + n] = acc[mt][r];
    }
    __syncthreads();

    // ---- phase 4: residual + LayerNorm(64)
    {
        const float* zbuf = resf;
        const int d = t & 63;
        const int dg = t >> 6;
        const float g  = gamma[d];
        const float bt = beta[d];
        #pragma unroll 2
        for (int i = 0; i < 8; ++i) {
            int q = dg + 4 * i;
            float z = zbuf[q * 68 + d] + x[(base + l0 + q) * 64 + d];
            float zsum = z;
            #pragma unroll
            for (int off = 32; off > 0; off >>= 1) zsum += __shfl_xor(zsum, off);
            float mu = zsum * 0.015625f;
            float dz = z - mu;
            float vsum = dz * dz;
            #pragma unroll
            for (int off = 32; off > 0; off >>= 1) vsum += __shfl_xor(vsum, off);
            float inv = rsqrtf(vsum * 0.015625f + 1e-3f);
            out[(base + l0 + q) * 64 + d] = g * dz * inv + bt;
        }
    }
}

extern "C" void kernel_launch(void* const* d_in, const int* in_sizes, int n_in,
                              void* d_out, int out_size, void* d_ws, size_t ws_size,
                              hipStream_t stream) {
    const float* x      = (const float*)d_in[0];
    const float* W_in   = (const float*)d_in[1];
    const float* conv_w = (const float*)d_in[2];
    const float* conv_b = (const float*)d_in[3];
    const float* W_x    = (const float*)d_in[4];
    const float* W_dt   = (const float*)d_in[5];
    const float* b_dt   = (const float*)d_in[6];
    const float* W_out  = (const float*)d_in[7];
    const float* gamma  = (const float*)d_in[8];
    const float* beta   = (const float*)d_in[9];
    float* out = (float*)d_out;

    // workspace layout (bytes)
    __hip_bfloat16* s    = (__hip_bfloat16*)d_ws;                        // 56,623,104  [b][c][l]
    float*          sums = (float*)((char*)d_ws + 56623104);             //  3,538,944
    float*          csum = (float*)((char*)d_ws + 60162048);             //     65,536
    __hip_bfloat16* wti  = (__hip_bfloat16*)((char*)d_ws + 88477696);    //     16,384
    __hip_bfloat16* wpt  = (__hip_bfloat16*)((char*)d_ws + 88494080);    //     65,536
    __hip_bfloat16* wtr  = (__hip_bfloat16*)((char*)d_ws + 88559616);    //     16,384
    __hip_bfloat16* wot  = (__hip_bfloat16*)((char*)d_ws + 88576000);    //     16,384

    kW_w<<<1, 256, 0, stream>>>(W_in, W_x, W_dt, W_out, wti, wpt, wtr, wot);
    dim3 grid(NT, 2);
    kA<<<grid, 256, 0, stream>>>(x, wti, wpt, conv_w, conv_b, b_dt, s, sums);
    dim3 gridB(NCH, 2);
    kB1<<<gridB, 256, 0, stream>>>(sums, csum);
    kB2<<<1, 256, 0, stream>>>(csum);
    kB3<<<gridB, 128, 0, stream>>>(sums, csum);
    kC<<<grid, 256, 0, stream>>>(x, wtr, wot, gamma, beta, s, sums, out);
}

// Round 2
// 283.450 us; speedup vs baseline: 1.1496x; 1.1496x over previous
//
#include <hip/hip_runtime.h>
#include <hip/hip_bf16.h>
#include <math.h>

#define L_LEN 110592   // 48*48*48
#define TILE 32
#define NT 3456        // tiles per batch
#define NCH 64         // scan chunks per batch
#define TPC 54         // tiles per chunk (NT/NCH)
#define STRX 72        // staged-x LDS row stride (bf16): 144B rows, 16B-aligned
#define STRC 136       // conv-out LDS row stride (bf16): 272B rows (2-way reads)
#define RESS 132       // resf row stride (f32): breaks 4-way write conflict

typedef float  floatx4 __attribute__((ext_vector_type(4)));
typedef short  short8  __attribute__((ext_vector_type(8)));
typedef short  short4v __attribute__((ext_vector_type(4)));

// fast silu: v * rcp(1+exp(-v))
__device__ __forceinline__ float fast_silu(float v) {
    return v * __builtin_amdgcn_rcpf(1.f + __expf(-v));
}
// fast softplus: max(d,0) + log(1+exp(-|d|))
__device__ __forceinline__ float fast_softplus(float d) {
    return fmaxf(d, 0.f) + __logf(1.f + __expf(-fabsf(d)));
}
__device__ __forceinline__ short f2bf(float f) {
    __hip_bfloat16 h = __float2bfloat16(f);
    return *reinterpret_cast<short*>(&h);
}
__device__ __forceinline__ float bf2f(short s) {
    __hip_bfloat16 h = *reinterpret_cast<__hip_bfloat16*>(&s);
    return __bfloat162float(h);
}
__device__ __forceinline__ short8 pack_bf8(float4 a, float4 b) {
    short8 r;
    r[0] = f2bf(a.x); r[1] = f2bf(a.y); r[2] = f2bf(a.z); r[3] = f2bf(a.w);
    r[4] = f2bf(b.x); r[5] = f2bf(b.y); r[6] = f2bf(b.z); r[7] = f2bf(b.w);
    return r;
}

// ---------------------------------------------------------------------------
// kW_w: transposed bf16 weight copies.
//   wti[n][k] = W_in[k][n] (ssm), wtr[n][k] = W_in[k][128+n] (res), k<64
//   wpt[n][k] = n<128 ? W_x[k][n] : W_dt[k][n-128], k<128
//   wot[n][k] = W_out[k][n], n<64, k<128
// ---------------------------------------------------------------------------
__global__ __launch_bounds__(256) void kW_w(
    const float* __restrict__ W_in, const float* __restrict__ W_x,
    const float* __restrict__ W_dt, const float* __restrict__ W_out,
    __hip_bfloat16* __restrict__ wti, __hip_bfloat16* __restrict__ wpt,
    __hip_bfloat16* __restrict__ wtr, __hip_bfloat16* __restrict__ wot)
{
    const int t = threadIdx.x;
    for (int idx = t; idx < 128 * 64; idx += 256) {
        int n = idx >> 6, k = idx & 63;
        wti[idx] = __float2bfloat16(W_in[k * 256 + n]);
        wtr[idx] = __float2bfloat16(W_in[k * 256 + 128 + n]);
    }
    for (int idx = t; idx < 256 * 128; idx += 256) {
        int n = idx >> 7, k = idx & 127;
        float v = (n < 128) ? W_x[k * 144 + n] : W_dt[k * 128 + (n - 128)];
        wpt[idx] = __float2bfloat16(v);
    }
    for (int idx = t; idx < 64 * 128; idx += 256) {
        int n = idx >> 7, k = idx & 127;
        wot[idx] = __float2bfloat16(W_out[k * 64 + n]);
    }
}

// ---------------------------------------------------------------------------
// kA (MFMA): cooperative bf16 x staging -> in-proj MFMA -> conv-in-registers
// (cross-lane shuffles) + silu -> projections -> s + sums.
// s layout: [b][tile][c][l_in_tile] — each block writes one contiguous 8KB
// region, so every L2 line is fully covered by one block (no RMW).
// ---------------------------------------------------------------------------
__global__ __launch_bounds__(256, 8) void kA(
    const float* __restrict__ x,
    const __hip_bfloat16* __restrict__ wti,
    const __hip_bfloat16* __restrict__ wpt,
    const float* __restrict__ conv_w, const float* __restrict__ conv_b,
    const float* __restrict__ b_dt,
    __hip_bfloat16* __restrict__ s, float* __restrict__ sums)
{
    __shared__ __align__(16) __hip_bfloat16 xbf[48 * STRX];  // 6912 B
    __shared__ __align__(16) __hip_bfloat16 xcb[32 * STRC];  // 8704 B

    const int t = threadIdx.x;
    const int lane = t & 63;
    const int w = t >> 6;
    const int quad = lane >> 4;
    const int lr = lane & 15;
    const int tile = blockIdx.x;
    const int b = blockIdx.y;
    const int l0 = tile * TILE;

    // ---- stage: x rows l0-1 .. l0+46 (48 rows x 64ch) -> bf16 LDS, once
    for (int idx = t; idx < 384; idx += 256) {
        const int row = idx >> 3, c8 = (idx & 7) << 3;
        const long gr = (long)l0 - 1 + row;
        float4 u0 = {0.f, 0.f, 0.f, 0.f}, u1 = {0.f, 0.f, 0.f, 0.f};
        if (gr >= 0 && gr < L_LEN) {
            const float* xp = x + (((long)b * L_LEN + gr) << 6) + c8;
            u0 = ((const float4*)xp)[0];
            u1 = ((const float4*)xp)[1];
        }
        *(short8*)&xbf[row * STRX + c8] = pack_bf8(u0, u1);
    }
    __syncthreads();

    // ---- phase 1: in-proj (M=48, N=128, K=64) + depthwise conv(4) + silu,
    //      conv done in accumulator registers via cross-lane shuffles.
    {
        floatx4 acc[3][2] = {};
        #pragma unroll
        for (int ks = 0; ks < 2; ++ks) {
            short8 bfr0 = *(const short8*)(wti + ((w * 32 + lr) << 6) + ks * 32 + quad * 8);
            short8 bfr1 = *(const short8*)(wti + ((w * 32 + 16 + lr) << 6) + ks * 32 + quad * 8);
            #pragma unroll
            for (int mt = 0; mt < 3; ++mt) {
                short8 afr = *(const short8*)&xbf[(mt * 16 + lr) * STRX + ks * 32 + quad * 8];
                acc[mt][0] = __builtin_amdgcn_mfma_f32_16x16x32_bf16(afr, bfr0, acc[mt][0], 0, 0, 0);
                acc[mt][1] = __builtin_amdgcn_mfma_f32_16x16x32_bf16(afr, bfr1, acc[mt][1], 0, 0, 0);
            }
        }
        // lane holds rows {mt*16 + quad*4 + r} for col w*32+jj*16+lr.
        // conv out[m] needs computed rows m..m+3; rows m+4..m+6 live in the
        // next quad (lane+16), wrapping into mt+1 when quad==3.
        const int srcLane = (((quad + 1) & 3) << 4) | lr;
        #pragma unroll
        for (int jj = 0; jj < 2; ++jj) {
            const int col = w * 32 + jj * 16 + lr;
            const float cw0 = conv_w[col],       cw1 = conv_w[128 + col];
            const float cw2 = conv_w[256 + col], cw3 = conv_w[384 + col];
            const float cb = conv_b[col];
            #pragma unroll
            for (int m = 0; m < 2; ++m) {
                float s0 = (quad == 0) ? acc[m + 1][jj][0] : acc[m][jj][0];
                float s1 = (quad == 0) ? acc[m + 1][jj][1] : acc[m][jj][1];
                float s2 = (quad == 0) ? acc[m + 1][jj][2] : acc[m][jj][2];
                const float e0 = __shfl(s0, srcLane);
                const float e1 = __shfl(s1, srcLane);
                const float e2 = __shfl(s2, srcLane);
                const float a0 = acc[m][jj][0], a1 = acc[m][jj][1];
                const float a2 = acc[m][jj][2], a3 = acc[m][jj][3];
                const int rb = m * 16 + quad * 4;
                xcb[(rb + 0) * STRC + col] =
                    __float2bfloat16(fast_silu(cb + cw0 * a0 + cw1 * a1 + cw2 * a2 + cw3 * a3));
                xcb[(rb + 1) * STRC + col] =
                    __float2bfloat16(fast_silu(cb + cw0 * a1 + cw1 * a2 + cw2 * a3 + cw3 * e0));
                xcb[(rb + 2) * STRC + col] =
                    __float2bfloat16(fast_silu(cb + cw0 * a2 + cw1 * a3 + cw2 * e0 + cw3 * e1));
                xcb[(rb + 3) * STRC + col] =
                    __float2bfloat16(fast_silu(cb + cw0 * a3 + cw1 * e0 + cw2 * e1 + cw3 * e2));
            }
        }
    }
    __syncthreads();

    // ---- phase 3: projections, s (tile-blocked channel-major) + sums
    {
        floatx4 accx[2][2] = {}, accd[2][2] = {};
        #pragma unroll
        for (int ks = 0; ks < 4; ++ks) {
            short8 afr[2];
            #pragma unroll
            for (int mt = 0; mt < 2; ++mt)
                afr[mt] = *(const short8*)&xcb[(mt * 16 + lr) * STRC + ks * 32 + quad * 8];
            #pragma unroll
            for (int j = 0; j < 2; ++j) {
                const int n = w * 32 + j * 16 + lr;
                short8 bx = *(const short8*)(wpt + (n << 7) + ks * 32 + quad * 8);
                short8 bd = *(const short8*)(wpt + ((n + 128) << 7) + ks * 32 + quad * 8);
                #pragma unroll
                for (int mt = 0; mt < 2; ++mt) {
                    accx[mt][j] = __builtin_amdgcn_mfma_f32_16x16x32_bf16(afr[mt], bx, accx[mt][j], 0, 0, 0);
                    accd[mt][j] = __builtin_amdgcn_mfma_f32_16x16x32_bf16(afr[mt], bd, accd[mt][j], 0, 0, 0);
                }
            }
        }
        const long tbase = ((long)b * NT + tile) << 7;   // tile base in cols
        float ps0 = 0.f, ps1 = 0.f;
        #pragma unroll
        for (int j = 0; j < 2; ++j) {
            const int col = w * 32 + j * 16 + lr;
            const float bdv = b_dt[col];
            __hip_bfloat16* sp = s + ((tbase + col) << 5) + quad * 4;
            float psl = 0.f;
            #pragma unroll
            for (int mt = 0; mt < 2; ++mt) {
                short4v pk;
                #pragma unroll
                for (int r = 0; r < 4; ++r) {
                    float dv = accd[mt][j][r] + bdv;
                    float sv = accx[mt][j][r] * fast_softplus(dv);
                    short h = f2bf(sv);
                    pk[r] = h;
                    psl += bf2f(h);
                }
                *(short4v*)(sp + mt * 16) = pk;
            }
            if (j == 0) ps0 = psl; else ps1 = psl;
        }
        ps0 += __shfl_xor(ps0, 16); ps0 += __shfl_xor(ps0, 32);
        ps1 += __shfl_xor(ps1, 16); ps1 += __shfl_xor(ps1, 32);
        const long sb = ((long)b * NT + tile) << 7;
        if (quad == 0)      sums[sb + w * 32 + lr] = ps0;
        else if (quad == 1) sums[sb + w * 32 + 16 + lr] = ps1;
    }
}

// ---------------------------------------------------------------------------
// kB1: per-chunk channel sums. grid(NCH, 2) x 256.
// ---------------------------------------------------------------------------
__global__ __launch_bounds__(256) void kB1(const float* __restrict__ sums,
                                           float* __restrict__ csum)
{
    __shared__ float ps[256];
    const int t = threadIdx.x;
    const int c = t & 127, h = t >> 7;
    const int ch = blockIdx.x, b = blockIdx.y;
    const long tb = ((long)b * NT + ch * TPC + h * 27) * 128 + c;
    float tot = 0.f;
    for (int j = 0; j < 27; j += 9) {
        float v[9];
        #pragma unroll
        for (int k = 0; k < 9; ++k) v[k] = sums[tb + (long)(j + k) * 128];
        #pragma unroll
        for (int k = 0; k < 9; ++k) tot += v[k];
    }
    ps[t] = tot;
    __syncthreads();
    if (t < 128) csum[((long)b * NCH + ch) * 128 + t] = ps[t] + ps[t + 128];
}

// ---------------------------------------------------------------------------
// kB2: exclusive scan over the 64 chunks, per (b, c). 1 block x 256.
// ---------------------------------------------------------------------------
__global__ __launch_bounds__(256) void kB2(float* __restrict__ csum)
{
    const int t = threadIdx.x;
    const int c = t & 127, b = t >> 7;
    const long base = (long)b * NCH * 128 + c;
    float run = 0.f;
    for (int ch = 0; ch < NCH; ch += 8) {
        float v[8];
        #pragma unroll
        for (int k = 0; k < 8; ++k) v[k] = csum[base + (long)(ch + k) * 128];
        #pragma unroll
        for (int k = 0; k < 8; ++k) {
            csum[base + (long)(ch + k) * 128] = run;
            run += v[k];
        }
    }
}

// ---------------------------------------------------------------------------
// kB3: rewrite sums -> exclusive tile prefix (chunk offset + in-chunk scan).
// grid(NCH, 2) x 128.
// ---------------------------------------------------------------------------
__global__ __launch_bounds__(128) void kB3(float* __restrict__ sums,
                                           const float* __restrict__ csum)
{
    const int c = threadIdx.x;
    const int ch = blockIdx.x, b = blockIdx.y;
    float run = csum[((long)b * NCH + ch) * 128 + c];
    const long tb = ((long)b * NT + ch * TPC) * 128 + c;
    for (int j = 0; j < TPC; j += 9) {
        float v[9];
        #pragma unroll
        for (int k = 0; k < 9; ++k) v[k] = sums[tb + (long)(j + k) * 128];
        #pragma unroll
        for (int k = 0; k < 9; ++k) {
            sums[tb + (long)(j + k) * 128] = run;
            run += v[k];
        }
    }
}

// ---------------------------------------------------------------------------
// kC (MFMA): staged bf16 x -> res-proj MFMA -> silu -> 2-way split scan
// (contiguous coalesced s loads, [b][tile][c][l]) + gate -> out-proj MFMA ->
// residual + LayerNorm(64).
// ---------------------------------------------------------------------------
__global__ __launch_bounds__(256, 6) void kC(
    const float* __restrict__ x,
    const __hip_bfloat16* __restrict__ wtr,
    const __hip_bfloat16* __restrict__ wot,
    const float* __restrict__ gamma, const float* __restrict__ beta,
    const __hip_bfloat16* __restrict__ s, const float* __restrict__ offs,
    float* __restrict__ out)
{
    __shared__ float resf[32 * RESS];                   // 16.9 KB; reused as zbuf
    __shared__ __align__(16) char ubuf[32 * STRC * 2];  // 8704 B: xbf then ybf
    __shared__ float totbuf[256];                       // 1 KB

    __hip_bfloat16* const ybf = (__hip_bfloat16*)ubuf;
    __hip_bfloat16* const xbf = (__hip_bfloat16*)ubuf;  // phase-1 only

    const int t = threadIdx.x;
    const int lane = t & 63;
    const int w = t >> 6;
    const int quad = lane >> 4;
    const int lr = lane & 15;
    const int tile = blockIdx.x;
    const int b = blockIdx.y;
    const int l0 = tile * TILE;
    const long base = (long)b * L_LEN;

    // ---- stage: x rows l0..l0+31 -> bf16 LDS (1 unit per thread)
    {
        const int row = t >> 3, c8 = (t & 7) << 3;
        const float* xp = x + ((base + l0 + row) << 6) + c8;
        float4 u0 = ((const float4*)xp)[0], u1 = ((const float4*)xp)[1];
        *(short8*)&xbf[row * STRX + c8] = pack_bf8(u0, u1);
    }
    __syncthreads();

    // ---- phase 1: res-proj MFMA (M=32, N=128, K=64), silu -> resf[m][c]
    {
        floatx4 acc[2][2] = {};
        #pragma unroll
        for (int ks = 0; ks < 2; ++ks) {
            short8 bfr0 = *(const short8*)(wtr + ((w * 32 + lr) << 6) + ks * 32 + quad * 8);
            short8 bfr1 = *(const short8*)(wtr + ((w * 32 + 16 + lr) << 6) + ks * 32 + quad * 8);
            #pragma unroll
            for (int mt = 0; mt < 2; ++mt) {
                short8 afr = *(const short8*)&xbf[(mt * 16 + lr) * STRX + ks * 32 + quad * 8];
                acc[mt][0] = __builtin_amdgcn_mfma_f32_16x16x32_bf16(afr, bfr0, acc[mt][0], 0, 0, 0);
                acc[mt][1] = __builtin_amdgcn_mfma_f32_16x16x32_bf16(afr, bfr1, acc[mt][1], 0, 0, 0);
            }
        }
        #pragma unroll
        for (int mt = 0; mt < 2; ++mt)
            #pragma unroll
            for (int j = 0; j < 2; ++j) {
                const int col = w * 32 + j * 16 + lr;
                #pragma unroll
                for (int r = 0; r < 4; ++r)
                    resf[(mt * 16 + quad * 4 + r) * RESS + col] = fast_silu(acc[mt][j][r]);
            }
    }
    __syncthreads();   // also retires xbf before ybf overwrites ubuf

    // ---- phase 2: 2-way split scan + gate (all 256 threads), y -> ybf bf16
    {
        const int c = t & 127, h = t >> 7;
        const __hip_bfloat16* sp = s + ((((long)b * NT + tile) << 7) + c) * 32 + h * 16;
        short8 sv0 = *(const short8*)sp;
        short8 sv1 = *(const short8*)(sp + 8);
        float pfx[16];
        float run = 0.f;
        #pragma unroll
        for (int i = 0; i < 8; ++i) { run += bf2f(sv0[i]); pfx[i] = run; }
        #pragma unroll
        for (int i = 0; i < 8; ++i) { run += bf2f(sv1[i]); pfx[8 + i] = run; }
        totbuf[t] = run;
        __syncthreads();
        float off = offs[((long)b * NT + tile) * 128 + c];
        if (h) off += totbuf[c];
        #pragma unroll
        for (int q = 0; q < 16; ++q)
            ybf[(h * 16 + q) * STRC + c] =
                __float2bfloat16(resf[(h * 16 + q) * RESS + c] * (off + pfx[q]));
    }
    __syncthreads();

    // ---- phase 3: out-proj MFMA (M=32, N=64, K=128) -> zbuf (=resf) [m][68]
    {
        float* zbuf = resf;
        floatx4 acc[2] = {};
        const int n = w * 16 + lr;
        #pragma unroll
        for (int ks = 0; ks < 4; ++ks) {
            short8 bfr = *(const short8*)(wot + (n << 7) + ks * 32 + quad * 8);
            #pragma unroll
            for (int mt = 0; mt < 2; ++mt) {
                short8 afr = *(const short8*)&ybf[(mt * 16 + lr) * STRC + ks * 32 + quad * 8];
                acc[mt] = __builtin_amdgcn_mfma_f32_16x16x32_bf16(afr, bfr, acc[mt], 0, 0, 0);
            }
        }
        __syncthreads();
        #pragma unroll
        for (int mt = 0; mt < 2; ++mt)
            #pragma unroll
            for (int r = 0; r < 4; ++r)
                zbuf[(mt * 16 + quad * 4 + r) * 68 + n] = acc[mt][r];
    }
    __syncthreads();

    // ---- phase 4: residual + LayerNorm(64)
    {
        const float* zbuf = resf;
        const int d = t & 63;
        const int dg = t >> 6;
        const float g  = gamma[d];
        const float bt = beta[d];
        #pragma unroll 2
        for (int i = 0; i < 8; ++i) {
            int q = dg + 4 * i;
            float z = zbuf[q * 68 + d] + x[(base + l0 + q) * 64 + d];
            float zsum = z;
            #pragma unroll
            for (int off = 32; off > 0; off >>= 1) zsum += __shfl_xor(zsum, off);
            float mu = zsum * 0.015625f;
            float dz = z - mu;
            float vsum = dz * dz;
            #pragma unroll
            for (int off = 32; off > 0; off >>= 1) vsum += __shfl_xor(vsum, off);
            float inv = rsqrtf(vsum * 0.015625f + 1e-3f);
            out[(base + l0 + q) * 64 + d] = g * dz * inv + bt;
        }
    }
}

extern "C" void kernel_launch(void* const* d_in, const int* in_sizes, int n_in,
                              void* d_out, int out_size, void* d_ws, size_t ws_size,
                              hipStream_t stream) {
    const float* x      = (const float*)d_in[0];
    const float* W_in   = (const float*)d_in[1];
    const float* conv_w = (const float*)d_in[2];
    const float* conv_b = (const float*)d_in[3];
    const float* W_x    = (const float*)d_in[4];
    const float* W_dt   = (const float*)d_in[5];
    const float* b_dt   = (const float*)d_in[6];
    const float* W_out  = (const float*)d_in[7];
    const float* gamma  = (const float*)d_in[8];
    const float* beta   = (const float*)d_in[9];
    float* out = (float*)d_out;

    // workspace layout (bytes)
    __hip_bfloat16* s    = (__hip_bfloat16*)d_ws;                        // 56,623,104  [b][tile][c][32]
    float*          sums = (float*)((char*)d_ws + 56623104);             //  3,538,944
    float*          csum = (float*)((char*)d_ws + 60162048);             //     65,536
    __hip_bfloat16* wti  = (__hip_bfloat16*)((char*)d_ws + 88477696);    //     16,384
    __hip_bfloat16* wpt  = (__hip_bfloat16*)((char*)d_ws + 88494080);    //     65,536
    __hip_bfloat16* wtr  = (__hip_bfloat16*)((char*)d_ws + 88559616);    //     16,384
    __hip_bfloat16* wot  = (__hip_bfloat16*)((char*)d_ws + 88576000);    //     16,384

    kW_w<<<1, 256, 0, stream>>>(W_in, W_x, W_dt, W_out, wti, wpt, wtr, wot);
    dim3 grid(NT, 2);
    kA<<<grid, 256, 0, stream>>>(x, wti, wpt, conv_w, conv_b, b_dt, s, sums);
    dim3 gridB(NCH, 2);
    kB1<<<gridB, 256, 0, stream>>>(sums, csum);
    kB2<<<1, 256, 0, stream>>>(csum);
    kB3<<<gridB, 128, 0, stream>>>(sums, csum);
    kC<<<grid, 256, 0, stream>>>(x, wtr, wot, gamma, beta, s, sums, out);
}